// Round 5
// baseline (204.188 us; speedup 1.0000x reference)
//
#include <hip/hip_runtime.h>

// ReconstructPatchImage: out[b,c,y,x] = sum of 8 permuted gathers of [B,HW,C] inputs.
// B=64, HW=196 (H=W=14), C=1024, float32.
//
// R4: per-wave private pipelines, ZERO barriers. Each of 7 waves owns rows
// q = 28w..28w+27 and a private 3-buffer LDS region (3 x 28x64 floats).
// Row perms applied on the global side of global_load_lds (closed-form diag
// ranks, no LUT memory); accumulate reads are linear+conflict-free.
// in2/in3 (channel-mixing col-major) via 28 float2 register loads.
// 2 batches chained per block; counted per-wave vmcnt, stores never gate.

#define N_C 1024
#define BSTRIDE (196 * 1024)

__device__ __forceinline__ int p5f(int y, int x) {   // diag TL->BR rank
    int s = x + y;
    int st = (s <= 13) ? ((s * (s + 1)) >> 1) : (105 + (((41 - s) * (s - 14)) >> 1));
    return st + y - ((s > 13) ? (s - 13) : 0);
}
__device__ __forceinline__ int p6f(int y, int x) {   // reversed-diag rank
    int s = x + y;
    int st = (s <= 13) ? ((s * (s + 1)) >> 1) : (105 + (((41 - s) * (s - 14)) >> 1));
    int x1 = (s < 13) ? s : 13;
    return 195 - st - (x1 - x);
}

__device__ __forceinline__ void gll16(const float* g, float* l) {
    __builtin_amdgcn_global_load_lds(
        (const __attribute__((address_space(1))) unsigned int*)g,
        (__attribute__((address_space(3))) unsigned int*)l,
        16, 0, 0);
}

#define SB()    __builtin_amdgcn_sched_barrier(0)
#define VMW(n)  asm volatile("s_waitcnt vmcnt(" #n ")" ::: "memory")

// stage one 28x64 slab for the wave: rows p = P(q), q = 28*w0 + r
template <int V>
__device__ __forceinline__ void stage(const float* gb, float* buf,
                                      int w0, int lane, int c0) {
    const int rlo = lane >> 4;          // row-within-quad
    const int ch4 = (lane & 15) << 2;   // channel sub-offset (floats)
    #pragma unroll
    for (int j = 0; j < 7; ++j) {
        int q = 28 * w0 + 4 * j + rlo;
        int y = (int)((unsigned)q / 14u);
        int x = q - y * 14;
        int p;
        if      constexpr (V == 0) p = q;
        else if constexpr (V == 1) p = 195 - q;
        else if constexpr (V == 4) p = p5f(y, x);
        else if constexpr (V == 5) p = p6f(y, x);
        else if constexpr (V == 6) p = p5f(y, 13 - x);
        else                       p = p5f(13 - y, x);
        (void)y; (void)x;
        gll16(gb + p * N_C + c0 + ch4, buf + j * 256);
    }
}

__global__ __launch_bounds__(448) void recon_kernel(
    const float* __restrict__ in0, const float* __restrict__ in1,
    const float* __restrict__ in2, const float* __restrict__ in3,
    const float* __restrict__ in4, const float* __restrict__ in5,
    const float* __restrict__ in6, const float* __restrict__ in7,
    float* __restrict__ out)
{
    __shared__ __align__(16) float lds[7 * 3 * 1792];   // 150,528 B
    const int tid  = threadIdx.x;
    const int lane = tid & 63;
    const int w0   = __builtin_amdgcn_readfirstlane(tid >> 6);  // 0..6
    const int c0   = blockIdx.x * 64;
    const int b0   = blockIdx.y * 2;

    float* buf0 = lds + w0 * 5376;
    float* buf1 = buf0 + 1792;
    float* buf2 = buf0 + 3584;

    float2 f2[28];
    float  a0[28], a1[28];

    // in2/in3 register loads for batch b: f2[0..13]=in2 per x, f2[14..27]=in3
    auto cm_issue = [&](int b) {
        const float* p2 = in2 + (size_t)b * BSTRIDE + (c0 + lane) * 14 + 2 * w0;
        #pragma unroll
        for (int x = 0; x < 14; ++x) f2[x] = *(const float2*)(p2 + x * 14336);
        const float* p3 = in3 + (size_t)b * BSTRIDE;
        int t = (c0 + lane) * 14 + 2 * w0;        // even -> pair never straddles %1024
        int hi = t >> 10, lo = t & 1023;
        #pragma unroll
        for (int x = 0; x < 14; ++x) {
            int p = 195 - x * 14 - hi;
            f2[14 + x] = *(const float2*)(p3 + p * N_C + lo);
        }
    };
    auto cm_acc = [&](float (&A)[28]) {           // initializes A
        #pragma unroll
        for (int x = 0; x < 14; ++x) { A[x] = f2[x].x;       A[14 + x] = f2[x].y; }
        #pragma unroll
        for (int x = 0; x < 14; ++x) { A[x] += f2[14 + x].x; A[14 + x] += f2[14 + x].y; }
    };
    auto accS = [&](float (&A)[28], const float* buf) {
        #pragma unroll
        for (int k = 0; k < 28; ++k) A[k] += buf[k * 64 + lane];
    };
    auto wstore = [&](int b, float (&A)[28]) {
        float* ob = out + (size_t)b * BSTRIDE + (size_t)(c0 + lane) * 196 + 28 * w0;
        #pragma unroll
        for (int j = 0; j < 7; ++j) {
            float4 v = make_float4(A[4*j], A[4*j+1], A[4*j+2], A[4*j+3]);
            *(float4*)(ob + 4 * j) = v;
        }
    };

    const float* B0  = (const float*)0;
    #define GB(ptr, b) ((ptr) + (size_t)(b) * BSTRIDE)
    (void)B0;

    // ---- batch b0: issue F, then 3 slabs ----
    cm_issue(b0); SB();
    stage<0>(GB(in0, b0), buf0, w0, lane, c0); SB();
    stage<1>(GB(in1, b0), buf1, w0, lane, c0); SB();
    stage<4>(GB(in4, b0), buf2, w0, lane, c0); SB();
    cm_acc(a0); SB();                               // compiler waits F only (21 gll16 stay in flight)

    VMW(14); SB(); accS(a0, buf0); SB(); stage<5>(GB(in5, b0), buf0, w0, lane, c0); SB();
    VMW(14); SB(); accS(a0, buf1); SB(); stage<6>(GB(in6, b0), buf1, w0, lane, c0); SB();
    VMW(14); SB(); accS(a0, buf2); SB(); stage<7>(GB(in7, b0), buf2, w0, lane, c0); SB();

    // ---- overlap into batch b0+1 ----
    VMW(14); SB(); accS(a0, buf0); SB();
    cm_issue(b0 + 1); SB();
    stage<0>(GB(in0, b0 + 1), buf0, w0, lane, c0); SB();

    VMW(42); SB(); accS(a0, buf1); SB(); stage<1>(GB(in1, b0 + 1), buf1, w0, lane, c0); SB();
    VMW(42); SB(); accS(a0, buf2); SB(); stage<4>(GB(in4, b0 + 1), buf2, w0, lane, c0); SB();

    cm_acc(a1); SB();                               // waits F(b1); S0',S1',S2' in flight

    VMW(14); SB(); accS(a1, buf0); SB(); stage<5>(GB(in5, b0 + 1), buf0, w0, lane, c0); SB();
    VMW(14); SB(); accS(a1, buf1); SB(); stage<6>(GB(in6, b0 + 1), buf1, w0, lane, c0); SB();
    VMW(14); SB(); accS(a1, buf2); SB(); stage<7>(GB(in7, b0 + 1), buf2, w0, lane, c0); SB();

    wstore(b0, a0); SB();                           // batch-0 output; never gates a wait

    VMW(21); SB(); accS(a1, buf0); SB();
    VMW(14); SB(); accS(a1, buf1); SB();
    VMW(7);  SB(); accS(a1, buf2); SB();

    wstore(b0 + 1, a1);
    #undef GB
}

extern "C" void kernel_launch(void* const* d_in, const int* in_sizes, int n_in,
                              void* d_out, int out_size, void* d_ws, size_t ws_size,
                              hipStream_t stream) {
    dim3 grid(16, 32);   // x: channel tile (1024/64), y: batch pair (64/2)
    dim3 block(448);     // 7 independent wave-pipelines; wave w owns q = 28w..28w+27
    recon_kernel<<<grid, block, 0, stream>>>(
        (const float*)d_in[0], (const float*)d_in[1], (const float*)d_in[2],
        (const float*)d_in[3], (const float*)d_in[4], (const float*)d_in[5],
        (const float*)d_in[6], (const float*)d_in[7], (float*)d_out);
}

// Round 6
// 103.926 us; speedup vs baseline: 1.9647x; 1.9647x over previous
//
#include <hip/hip_runtime.h>

// ReconstructPatchImage: out[b,c,y,x] = sum of 8 permuted gathers of [B,HW,C] inputs.
// B=64, HW=196 (H=W=14), C=1024, float32.
//
// Per-input flat (per-batch) source index for output (c, q=y*14+x):
//   in0: q*1024+c   in1: (195-q)*1024+c
//   in2: x*14336 + c*14 + y                      (channel-mixing col-major)
//   in3: (195 - x*14 - hi)*1024 + lo, t=c*14+y   (reversed col-major)
//   in4: p5f(y,x)   in5: p6f(y,x)   in6: p5f(y,13-x)   in7: p5f(13-y,x)
//
// R5: R2's lockstep counted-vmcnt pipeline (proven clean FETCH/WRITE) but at
// c-tile 32 -> slab 24.5 KB, 3 buffers = 73.5 KB -> TWO resident blocks/CU.
// Cross-block overlap hides prologue/epilogue/convoy stalls. Slab staged as
// 24 x width-16 + 2 x width-4 global_load_lds (waves 0-5: 4 instr/slab,
// wave 6: 2; vmcnt immediates branch on wave id - uniform scalar branch).
// Row perms applied acc-side from packed precomputed registers (pure VALU,
// nothing pollutes the vmcnt FIFO). Epilogue store = R2's exact clean pattern.

#define N_C   1024
#define BSTR  (196 * 1024)
#define SLABF 6272            // floats per 196x32 slab

__device__ __forceinline__ int p5f(int y, int x) {   // diag TL->BR rank
    int s = x + y;
    int st = (s <= 13) ? ((s * (s + 1)) >> 1) : (105 + (((41 - s) * (s - 14)) >> 1));
    return st + y - ((s > 13) ? (s - 13) : 0);
}
__device__ __forceinline__ int p6f(int y, int x) {   // reversed-diag rank
    int s = x + y;
    int st = (s <= 13) ? ((s * (s + 1)) >> 1) : (105 + (((41 - s) * (s - 14)) >> 1));
    int x1 = (s < 13) ? s : 13;
    return 195 - st - (x1 - x);
}

__device__ __forceinline__ void gll16(const float* g, float* l) {
    __builtin_amdgcn_global_load_lds(
        (const __attribute__((address_space(1))) unsigned int*)g,
        (__attribute__((address_space(3))) unsigned int*)l, 16, 0, 0);
}
__device__ __forceinline__ void gll4(const float* g, float* l) {
    __builtin_amdgcn_global_load_lds(
        (const __attribute__((address_space(1))) unsigned int*)g,
        (__attribute__((address_space(3))) unsigned int*)l, 4, 0, 0);
}

#define BAR()   __builtin_amdgcn_s_barrier()
#define VMW(n)  asm volatile("s_waitcnt vmcnt(" #n ")" ::: "memory")
#define LGKM0   asm volatile("s_waitcnt lgkmcnt(0)" ::: "memory")

__global__ __launch_bounds__(448) void recon_kernel(
    const float* __restrict__ in0, const float* __restrict__ in1,
    const float* __restrict__ in2, const float* __restrict__ in3,
    const float* __restrict__ in4, const float* __restrict__ in5,
    const float* __restrict__ in6, const float* __restrict__ in7,
    float* __restrict__ out)
{
    __shared__ __align__(16) float lds[3 * SLABF];   // 75,264 B -> 2 blocks/CU
    const int tid  = threadIdx.x;
    const int lane = tid & 63;
    const int chl  = lane & 31;                              // channel within tile
    const int qh   = lane >> 5;                              // q parity half
    const int w0   = __builtin_amdgcn_readfirstlane(tid >> 6);  // 0..6
    const int c0   = blockIdx.x * 32;                        // channel tile base
    const int b    = blockIdx.y;
    const size_t boff = (size_t)b * BSTR;

    float* buf0 = lds;
    float* buf1 = lds + SLABF;
    float* buf2 = lds + 2 * SLABF;

    // ---- staging: slab = 24 x w16 (waves 0-5, 4 each) + 2 x w4 (wave 6) ----
    auto stageLIN = [&](const float* gb, float* sb) {
        if (w0 < 6) {
            #pragma unroll
            for (int jj = 0; jj < 4; ++jj) {
                int J   = w0 * 4 + jj;
                int gi  = J * 64 + lane;
                int row = gi >> 3;
                int co  = (gi & 7) * 4;
                gll16(gb + row * N_C + c0 + co, sb + J * 256);
            }
        } else {
            #pragma unroll
            for (int i2 = 0; i2 < 2; ++i2) {
                int fi  = 6144 + i2 * 64 + lane;
                int row = fi >> 5;
                int ch  = fi & 31;
                gll4(gb + row * N_C + c0 + ch, sb + 6144 + i2 * 64);
            }
        }
    };
    auto stageCM2 = [&](const float* gb, float* sb) {        // in2 forward
        if (w0 < 6) {
            #pragma unroll
            for (int jj = 0; jj < 4; ++jj) {
                int J  = w0 * 4 + jj;
                int gi = J * 64 + lane;
                int x  = gi / 112;
                int r4 = (gi - x * 112) * 4;
                gll16(gb + x * 14336 + c0 * 14 + r4, sb + J * 256);
            }
        } else {
            #pragma unroll
            for (int i2 = 0; i2 < 2; ++i2) {
                int fi = 6144 + i2 * 64 + lane;
                int r  = fi - 5824;                          // all remainder is x=13
                gll4(gb + 13 * 14336 + c0 * 14 + r, sb + 6144 + i2 * 64);
            }
        }
    };
    auto stageCM3 = [&](const float* gb, float* sb) {        // in3 reversed
        if (w0 < 6) {
            #pragma unroll
            for (int jj = 0; jj < 4; ++jj) {
                int J  = w0 * 4 + jj;
                int gi = J * 64 + lane;
                int x  = gi / 112;
                int r4 = (gi - x * 112) * 4;
                int t  = c0 * 14 + r4;                       // 16B group never straddles %1024
                int hi = t >> 10, lo = t & 1023;
                int p  = 195 - x * 14 - hi;
                gll16(gb + p * N_C + lo, sb + J * 256);
            }
        } else {
            #pragma unroll
            for (int i2 = 0; i2 < 2; ++i2) {
                int fi = 6144 + i2 * 64 + lane;
                int r  = fi - 5824;
                int t  = c0 * 14 + r;
                int hi = t >> 10, lo = t & 1023;
                int p  = 13 - hi;                            // 195 - 13*14 - hi
                gll4(gb + p * N_C + lo, sb + 6144 + i2 * 64);
            }
        }
    };

    // ---- issue first 3 slabs, then do VALU precompute under the latency ----
    stageLIN(in0 + boff, buf0);
    stageLIN(in1 + boff, buf1);
    stageCM2(in2 + boff, buf2);

    // packed per-thread perm rows (pure VALU -> nothing enters vmcnt FIFO)
    unsigned pp45[14], pp67[14];
    int cmoff[14];
    #pragma unroll
    for (int k = 0; k < 14; ++k) {
        int q = 28 * w0 + 2 * k + qh;
        int y = q / 14;
        int x = q - 14 * y;
        pp45[k] = (unsigned)p5f(y, x) | ((unsigned)p6f(y, x) << 16);
        pp67[k] = (unsigned)p5f(y, 13 - x) | ((unsigned)p5f(13 - y, x) << 16);
        cmoff[k] = x * 448 + chl * 14 + y;
    }

    float acc[14];
    auto accL = [&](const float* sb, auto pf, bool first) {
        #pragma unroll
        for (int k = 0; k < 14; ++k) {
            int p = pf(k);
            float v = sb[p * 32 + chl];
            if (first) acc[k] = v; else acc[k] += v;
        }
    };
    auto accCM = [&](const float* sb) {
        #pragma unroll
        for (int k = 0; k < 14; ++k) acc[k] += sb[cmoff[k]];
    };

    // per-wave depth-2 waits: waves 0-5 have 4 loads/slab, wave 6 has 2
    #define VMW_D2  do { if (w0 < 6) { VMW(8); } else { VMW(4); } } while (0)
    #define VMW_D1  do { if (w0 < 6) { VMW(4); } else { VMW(2); } } while (0)

    // P0..P7: wait slab i, acc, prefetch slab i+3
    VMW_D2; BAR();
    accL(buf0, [&](int k){ return 28 * w0 + 2 * k + qh; }, true);
    LGKM0; BAR(); stageCM3(in3 + boff, buf0);

    VMW_D2; BAR();
    accL(buf1, [&](int k){ return 195 - (28 * w0 + 2 * k + qh); }, false);
    LGKM0; BAR(); stageLIN(in4 + boff, buf1);

    VMW_D2; BAR();
    accCM(buf2);
    LGKM0; BAR(); stageLIN(in5 + boff, buf2);

    VMW_D2; BAR();
    accCM(buf0);
    LGKM0; BAR(); stageLIN(in6 + boff, buf0);

    VMW_D2; BAR();
    accL(buf1, [&](int k){ return (int)(pp45[k] & 0xffffu); }, false);
    LGKM0; BAR(); stageLIN(in7 + boff, buf1);

    VMW_D2; BAR();
    accL(buf2, [&](int k){ return (int)(pp45[k] >> 16); }, false);
    LGKM0; BAR();

    VMW_D1; BAR();
    accL(buf0, [&](int k){ return (int)(pp67[k] & 0xffffu); }, false);
    LGKM0; BAR();

    VMW(0); BAR();
    accL(buf1, [&](int k){ return (int)(pp67[k] >> 16); }, false);

    // ---- epilogue: LDS transpose (stride 33) + contiguous scalar stores ----
    __syncthreads();                       // all buf reads done before overwrite
    float* tr = lds;                       // 196*33 = 6468 floats
    #pragma unroll
    for (int k = 0; k < 14; ++k) {
        int q = 28 * w0 + 2 * k + qh;
        tr[q * 33 + chl] = acc[k];
    }
    __syncthreads();
    float* ob = out + boff + (size_t)c0 * 196;
    #pragma unroll
    for (int k = 0; k < 14; ++k) {
        int i  = tid + k * 448;            // 0..6271, contiguous per wave
        int cg = i / 196;
        int q  = i - cg * 196;
        ob[cg * 196 + q] = tr[q * 33 + cg];
    }
    #undef VMW_D2
    #undef VMW_D1
}

extern "C" void kernel_launch(void* const* d_in, const int* in_sizes, int n_in,
                              void* d_out, int out_size, void* d_ws, size_t ws_size,
                              hipStream_t stream) {
    dim3 grid(32, 64);   // x: channel tile (1024/32), y: batch
    dim3 block(448);     // 7 waves; wave w owns q = 28w..28w+27 (2 q per lane-half)
    recon_kernel<<<grid, block, 0, stream>>>(
        (const float*)d_in[0], (const float*)d_in[1], (const float*)d_in[2],
        (const float*)d_in[3], (const float*)d_in[4], (const float*)d_in[5],
        (const float*)d_in[6], (const float*)d_in[7], (float*)d_out);
}

// Round 7
// 98.354 us; speedup vs baseline: 2.0761x; 1.0567x over previous
//
#include <hip/hip_runtime.h>

// ReconstructPatchImage: out[b,c,y,x] = sum of 8 permuted gathers of [B,HW,C] inputs.
// B=64, HW=196 (H=W=14), C=1024, float32.
//
// Per-input flat (per-batch) source index for output (c, q=y*14+x):
//   in0: q*1024+c   in1: (195-q)*1024+c
//   in2: x*14336 + c*14 + y                      (channel-mixing col-major)
//   in3: (195 - x*14 - hi)*1024 + lo, t=c*14+y   (reversed col-major)
//   in4: p5f(y,x)   in5: p6f(y,x)   in6: p5f(y,13-x)   in7: p5f(13-y,x)
//
// R6 = R2 skeleton (c-tile 64, 3-buffer counted-vmcnt lockstep pipeline,
// proven FETCH=200.8MB / WRITE=50.2MB clean) + two device-level changes:
//  (a) per-block INPUT-ORDER ROTATION (accumulation is commutative; every
//      stage variant is exactly 7 gll16/wave so vmcnt immediates unchanged)
//      -> decorrelates the 8 read streams across the device, spreading DRAM
//      bank/row pressure instead of all 1024 blocks hammering one input.
//  (b) nontemporal output stores -> don't evict L3-resident input bytes.

#define N_C   1024
#define BSTR  (196 * 1024)
#define SLABF 12544          // floats per 196x64 slab

__device__ __forceinline__ int p5f(int y, int x) {   // diag TL->BR rank
    int s = x + y;
    int st = (s <= 13) ? ((s * (s + 1)) >> 1) : (105 + (((41 - s) * (s - 14)) >> 1));
    return st + y - ((s > 13) ? (s - 13) : 0);
}
__device__ __forceinline__ int p6f(int y, int x) {   // reversed-diag rank
    int s = x + y;
    int st = (s <= 13) ? ((s * (s + 1)) >> 1) : (105 + (((41 - s) * (s - 14)) >> 1));
    int x1 = (s < 13) ? s : 13;
    return 195 - st - (x1 - x);
}

__device__ __forceinline__ void gll16(const float* g, float* l) {
    __builtin_amdgcn_global_load_lds(
        (const __attribute__((address_space(1))) unsigned int*)g,
        (__attribute__((address_space(3))) unsigned int*)l, 16, 0, 0);
}

#define BAR()   __builtin_amdgcn_s_barrier()
#define VMW(n)  asm volatile("s_waitcnt vmcnt(" #n ")" ::: "memory")
#define LGKM0   asm volatile("s_waitcnt lgkmcnt(0)" ::: "memory")

__global__ __launch_bounds__(448) void recon_kernel(
    const float* __restrict__ in0, const float* __restrict__ in1,
    const float* __restrict__ in2, const float* __restrict__ in3,
    const float* __restrict__ in4, const float* __restrict__ in5,
    const float* __restrict__ in6, const float* __restrict__ in7,
    float* __restrict__ out)
{
    __shared__ __align__(16) float lds[3 * SLABF];   // 150,528 B
    const int tid  = threadIdx.x;
    const int lane = tid & 63;
    const int w0   = __builtin_amdgcn_readfirstlane(tid >> 6);  // 0..6
    const int c0   = blockIdx.x * 64;
    const int b    = blockIdx.y;
    const size_t boff = (size_t)b * BSTR;
    const int rot  = (blockIdx.x + 3 * blockIdx.y) & 7;

    const float* ins[8] = { in0, in1, in2, in3, in4, in5, in6, in7 };

    // ---- stage input ii into slab sb: always 7 gll16 per wave ----
    auto stage_any = [&](int ii, float* sb) {
        const float* gb = ins[ii] + boff;
        if (ii == 2) {                        // col-major forward: contiguous 896-float runs per x
            #pragma unroll
            for (int j = 0; j < 7; ++j) {
                int ch = w0 + 7 * j;
                int i  = ch * 64 + lane;
                int x  = i / 224;
                int r  = i - x * 224;
                gll16(gb + x * 14336 + c0 * 14 + r * 4, sb + ch * 256);
            }
        } else if (ii == 3) {                 // col-major reversed
            #pragma unroll
            for (int j = 0; j < 7; ++j) {
                int ch = w0 + 7 * j;
                int i  = ch * 64 + lane;
                int x  = i / 224;
                int jj4 = (i - x * 224) << 2;
                int t  = c0 * 14 + jj4;       // 16B group never straddles t%1024
                int hi = t >> 10, lo = t & 1023;
                int p  = 195 - x * 14 - hi;
                gll16(gb + p * N_C + lo, sb + ch * 256);
            }
        } else {                              // row-layout inputs staged linearly
            #pragma unroll
            for (int j = 0; j < 7; ++j) {
                int ch = w0 + 7 * j;
                int i  = ch * 64 + lane;
                int p  = i >> 4;
                int rf = (i & 15) << 2;
                gll16(gb + p * N_C + c0 + rf, sb + ch * 256);
            }
        }
    };

    float acc[28];
    #pragma unroll
    for (int k = 0; k < 28; ++k) acc[k] = 0.f;

    #define ACCP(EXPR)                                        \
        do {                                                  \
            _Pragma("unroll")                                 \
            for (int k = 0; k < 28; ++k) {                    \
                const int q = 28 * w0 + k;                    \
                const int y = 2 * w0 + (k / 14);              \
                const int x = k % 14;                         \
                (void)q; (void)y; (void)x;                    \
                acc[k] += sb[(EXPR) * 64 + lane];             \
            }                                                 \
        } while (0)

    auto acc_any = [&](int ii, const float* sb) {
        if (ii == 2 || ii == 3) {
            #pragma unroll
            for (int x = 0; x < 14; ++x) {
                float2 v = *(const float2*)(sb + x * 896 + lane * 14 + 2 * w0);
                acc[x]      += v.x;
                acc[14 + x] += v.y;
            }
        }
        else if (ii == 0) ACCP(q);
        else if (ii == 1) ACCP(195 - q);
        else if (ii == 4) ACCP(p5f(y, x));
        else if (ii == 5) ACCP(p6f(y, x));
        else if (ii == 6) ACCP(p5f(y, 13 - x));
        else              ACCP(p5f(13 - y, x));
    };

    // ---- prologue: 3 slabs in flight ----
    stage_any((0 + rot) & 7, lds);
    stage_any((1 + rot) & 7, lds + SLABF);
    stage_any((2 + rot) & 7, lds + 2 * SLABF);

    // ---- 8 phases, counted vmcnt (7 loads/wave/slab), never drain early ----
    #pragma unroll 1
    for (int s = 0; s < 8; ++s) {
        if (s < 6)       { VMW(14); }
        else if (s == 6) { VMW(7);  }
        else             { VMW(0);  }
        BAR();
        float* sb = lds + (s % 3) * SLABF;
        acc_any((s + rot) & 7, sb);
        LGKM0; BAR();
        if (s + 3 < 8) stage_any((s + 3 + rot) & 7, sb);
    }
    #undef ACCP

    // ---- epilogue: LDS transpose (stride 65) + nontemporal coalesced stores ----
    __syncthreads();
    float* tr = lds;                      // 196*65 = 12740 floats
    #pragma unroll
    for (int k = 0; k < 28; ++k) {
        int q = 28 * w0 + k;
        tr[q * 65 + lane] = acc[k];
    }
    __syncthreads();
    float* ob = out + boff + (size_t)c0 * 196;
    #pragma unroll
    for (int k = 0; k < 28; ++k) {
        int i  = tid + k * 448;           // 0..12543
        int cg = i / 196;
        int q  = i - cg * 196;
        __builtin_nontemporal_store(tr[q * 65 + cg], ob + cg * 196 + q);
    }
}

extern "C" void kernel_launch(void* const* d_in, const int* in_sizes, int n_in,
                              void* d_out, int out_size, void* d_ws, size_t ws_size,
                              hipStream_t stream) {
    dim3 grid(16, 64);   // x: channel tile (1024/64), y: batch
    dim3 block(448);     // 7 waves; wave w owns q = 28w..28w+27
    recon_kernel<<<grid, block, 0, stream>>>(
        (const float*)d_in[0], (const float*)d_in[1], (const float*)d_in[2],
        (const float*)d_in[3], (const float*)d_in[4], (const float*)d_in[5],
        (const float*)d_in[6], (const float*)d_in[7], (float*)d_out);
}